// Round 4
// baseline (278.581 us; speedup 1.0000x reference)
//
#include <hip/hip_runtime.h>

// Multi-threshold spiking neuron scan. x: [T*B, C, H, W] fp32, T=4, K=8.
// Per column: mem += x[t]; spike = largest thre[k]=thresh/2^k with
// mem >= 0.75*thre[k]; out[t] = spike; mem -= spike.
//
// R1-R5: five structurally different kernels pinned at ~88us (VALUBusy 8-17%)
//   -> memory-system queuing, not issue or HBM bus.
// R6: XCD-segmented j-sweep (block b -> segment b%8) decorrelated the 8 XCD
//   fronts. Kernel now <79.5us (absent from rocprof top-5; fills are 80us).
// R7 (3rd resubmit after broker timeouts): contiguous 1024-col chunk per
//   block + 2-deep software pipeline. Each block emits 16KiB sequential per
//   stream (was 4KiB), grid drops 8192->2048 (fewer in-phase DRAM fronts),
//   reads batch ahead of writes (fewer bus turnarounds), 8 loads in flight
//   before first use.

constexpr int T_STEPS = 4;
constexpr int BLOCK   = 256;
constexpr int UNROLL  = 4;                  // iterations per chunk
constexpr int CHUNK   = BLOCK * UNROLL;     // 1024 float4 columns per block
constexpr int NXCD    = 8;

typedef float v4f __attribute__((ext_vector_type(4)));

// Exact spike via fp32 bit ordering (thresh > 0 normal, mem non-NaN):
// positive fp32 compare == int compare of bits; thr75[k] bits = b75_0 - k*2^23;
// k* = max(0, ceil((b75_0 - bits(mem)) / 2^23)); spike bits = bth0 - k*·2^23;
// mem < thr75[7] (incl. mem<=0, signed cmp) -> 0.  Verified absmax=0 in R5/R6.
__device__ __forceinline__ float spike_of(float mem, int b75_0, int b75_7, int bth0) {
    int u = __float_as_int(mem);
    int d = (int)((unsigned)b75_0 - (unsigned)u);
    int k = (int)((unsigned)d + 0x7fffffu) >> 23;
    k = k > 0 ? k : 0;
    int sb = bth0 - (k << 23);
    return (u >= b75_7) ? __int_as_float(sb) : 0.0f;
}

__global__ __launch_bounds__(BLOCK) void snn_mth_kernel(
    const float* __restrict__ x,
    const float* __restrict__ p_thresh,
    float* __restrict__ out,
    int s4)   // float4 columns per timestep
{
    const float thresh = *p_thresh;
    const int bth0  = __float_as_int(thresh);
    const int b75_0 = __float_as_int(0.75f * thresh);
    const int b75_7 = b75_0 - 7 * 0x800000;

    const v4f* __restrict__ xv = reinterpret_cast<const v4f*>(x);
    v4f* __restrict__ ov = reinterpret_cast<v4f*>(out);

    // Bijective XCD swizzle over chunk index (m204 formula): block b on XCD
    // b%8 gets a chunk inside that XCD's contiguous 1/8 of the column space,
    // so the 8 XCDs' read/write fronts stay decorrelated (R6 lesson) while
    // each block sweeps 16KiB sequential per stream.
    const int nwg  = (int)gridDim.x;
    const int b    = (int)blockIdx.x;
    const int q    = nwg / NXCD, r = nwg % NXCD;
    const int xcd  = b % NXCD;
    const int slot = b / NXCD;
    const int c    = (xcd < r ? xcd * (q + 1) : r * (q + 1) + (xcd - r) * q) + slot;

    const size_t n    = (size_t)s4;
    const size_t base = (size_t)c * CHUNK + threadIdx.x;

    v4f bufA[T_STEPS], bufB[T_STEPS];

    auto LOAD = [&](v4f (&buf)[T_STEPS], int i) {
        const size_t j = base + (size_t)i * BLOCK;
        if (j < n) {
#pragma unroll
            for (int t = 0; t < T_STEPS; ++t)
                buf[t] = xv[(size_t)t * n + j];
        }
    };

    auto PROC = [&](v4f (&buf)[T_STEPS], int i) {
        const size_t j = base + (size_t)i * BLOCK;
        if (j < n) {
            v4f sp[T_STEPS];
#pragma unroll
            for (int e = 0; e < 4; ++e) {
                float mem = buf[0][e];
                float s0 = spike_of(mem, b75_0, b75_7, bth0);
                sp[0][e] = s0;
                mem = mem - s0 + buf[1][e];
                float s1 = spike_of(mem, b75_0, b75_7, bth0);
                sp[1][e] = s1;
                mem = mem - s1 + buf[2][e];
                float s2 = spike_of(mem, b75_0, b75_7, bth0);
                sp[2][e] = s2;
                mem = mem - s2 + buf[3][e];
                sp[3][e] = spike_of(mem, b75_0, b75_7, bth0);
            }
#pragma unroll
            for (int t = 0; t < T_STEPS; ++t)
                __builtin_nontemporal_store(sp[t], &ov[(size_t)t * n + j]);
        }
    };

    // 2-deep software pipeline over the 4 chunk iterations (all indices
    // compile-time static -> no scratch, rule #20).
    LOAD(bufA, 0);
    LOAD(bufB, 1);
    PROC(bufA, 0);
    LOAD(bufA, 2);
    PROC(bufB, 1);
    LOAD(bufB, 3);
    PROC(bufA, 2);
    PROC(bufB, 3);
}

extern "C" void kernel_launch(void* const* d_in, const int* in_sizes, int n_in,
                              void* d_out, int out_size, void* d_ws, size_t ws_size,
                              hipStream_t stream) {
    const float* x = (const float*)d_in[0];
    const float* p_thresh = (const float*)d_in[1];
    float* out = (float*)d_out;

    const int total = in_sizes[0];          // T*B*C*H*W
    const int S = total / T_STEPS;          // spatial elements per timestep
    const int s4 = S >> 2;                  // float4 columns

    const int grid = (s4 + CHUNK - 1) / CHUNK;
    snn_mth_kernel<<<grid, BLOCK, 0, stream>>>(x, p_thresh, out, s4);
}

// Round 5
// 242.099 us; speedup vs baseline: 1.1507x; 1.1507x over previous
//
#include <hip/hip_runtime.h>

// Multi-threshold spiking neuron scan. x: [T*B, C, H, W] fp32, T=4, K=8.
// Per column: mem += x[t]; spike = largest thre[k]=thresh/2^k with
// mem >= 0.75*thre[k]; out[t] = spike; mem -= spike.
//
// R1-R5: five structurally different kernels pinned at ~88us -> memory-system
//   queuing, not issue or HBM bus.
// R6: XCD-segmented j-sweep, BLOCK=256, 1 col/thread: kernel ~80us
//   (2.5 TB/s HBM; FETCH halved by L3 thanks to NT stores).
// R7 FAILED (126us): 4-col/thread chunk + 2-deep SW pipeline. VGPR=32 shows
//   the compiler collapsed the pipeline (re-serialized); grid 2048*4waves =
//   exactly 1 machine fill -> no TLP to hide the serialized chains.
//   Lesson: expand BLOCK footprint via waves, never wave footprint via loops.
// R8 (this): R6 per-thread structure exactly, BLOCK=1024. Same 32768-wave
//   oversubscription (4x), but each block emits 16KiB sequential per stream
//   from one CU (the R7 locality goal achieved via TLP, not per-wave loops).

constexpr int T_STEPS = 4;
constexpr int BLOCK   = 1024;
constexpr int NXCD    = 8;

typedef float v4f __attribute__((ext_vector_type(4)));

// Exact spike via fp32 bit ordering (thresh > 0 normal, mem non-NaN):
// positive fp32 compare == int compare of bits; thr75[k] bits = b75_0 - k*2^23;
// k* = max(0, ceil((b75_0 - bits(mem)) / 2^23)); spike bits = bth0 - k*·2^23;
// mem < thr75[7] (incl. mem<=0, signed cmp) -> 0.  Verified absmax=0 R5-R7.
__device__ __forceinline__ float spike_of(float mem, int b75_0, int b75_7, int bth0) {
    int u = __float_as_int(mem);
    int d = (int)((unsigned)b75_0 - (unsigned)u);
    int k = (int)((unsigned)d + 0x7fffffu) >> 23;
    k = k > 0 ? k : 0;
    int sb = bth0 - (k << 23);
    return (u >= b75_7) ? __int_as_float(sb) : 0.0f;
}

__global__ __launch_bounds__(BLOCK) void snn_mth_kernel(
    const float* __restrict__ x,
    const float* __restrict__ p_thresh,
    float* __restrict__ out,
    int s4)   // float4 columns per timestep
{
    const float thresh = *p_thresh;
    const int bth0  = __float_as_int(thresh);
    const int b75_0 = __float_as_int(0.75f * thresh);
    const int b75_7 = b75_0 - 7 * 0x800000;

    const v4f* __restrict__ xv = reinterpret_cast<const v4f*>(x);
    v4f* __restrict__ ov = reinterpret_cast<v4f*>(out);

    // XCD-segmented mapping (R6): segment = b % NXCD (matches CP round-robin
    // block->XCD dispatch), slot = b / NXCD sweeps within the segment, so the
    // 8 XCDs' read/write fronts stay decorrelated.
    const int seg_cols   = s4 / (NXCD * BLOCK) * BLOCK;  // cols per segment (whole blocks)
    const int seg_blocks = seg_cols / BLOCK;
    const int main_blocks = seg_blocks * NXCD;

    const int b = blockIdx.x;
    size_t j;
    if (b < main_blocks) {
        const int xcd  = b % NXCD;
        const int slot = b / NXCD;
        j = (size_t)xcd * seg_cols + (size_t)slot * BLOCK + threadIdx.x;
    } else {
        // Tail (empty for the benchmark shape: s4 = 2^21 divides evenly).
        j = (size_t)NXCD * seg_cols + (size_t)(b - main_blocks) * BLOCK + threadIdx.x;
        if (j >= (size_t)s4) return;
    }

    const size_t n = (size_t)s4;

    v4f xc[T_STEPS];
#pragma unroll
    for (int t = 0; t < T_STEPS; ++t)
        xc[t] = xv[(size_t)t * n + j];

    v4f sp[T_STEPS];
#pragma unroll
    for (int e = 0; e < 4; ++e) {
        float mem = xc[0][e];
        float s0 = spike_of(mem, b75_0, b75_7, bth0);
        sp[0][e] = s0;
        mem = mem - s0 + xc[1][e];
        float s1 = spike_of(mem, b75_0, b75_7, bth0);
        sp[1][e] = s1;
        mem = mem - s1 + xc[2][e];
        float s2 = spike_of(mem, b75_0, b75_7, bth0);
        sp[2][e] = s2;
        mem = mem - s2 + xc[3][e];
        sp[3][e] = spike_of(mem, b75_0, b75_7, bth0);
    }

#pragma unroll
    for (int t = 0; t < T_STEPS; ++t)
        __builtin_nontemporal_store(sp[t], &ov[(size_t)t * n + j]);
}

extern "C" void kernel_launch(void* const* d_in, const int* in_sizes, int n_in,
                              void* d_out, int out_size, void* d_ws, size_t ws_size,
                              hipStream_t stream) {
    const float* x = (const float*)d_in[0];
    const float* p_thresh = (const float*)d_in[1];
    float* out = (float*)d_out;

    const int total = in_sizes[0];          // T*B*C*H*W
    const int S = total / T_STEPS;          // spatial elements per timestep
    const int s4 = S >> 2;                  // float4 columns

    const int grid = (s4 + BLOCK - 1) / BLOCK;
    snn_mth_kernel<<<grid, BLOCK, 0, stream>>>(x, p_thresh, out, s4);
}

// Round 6
// 235.599 us; speedup vs baseline: 1.1824x; 1.0276x over previous
//
#include <hip/hip_runtime.h>

// Multi-threshold spiking neuron scan. x: [T*B, C, H, W] fp32, T=4, K=8.
// Per column: mem += x[t]; spike = largest thre[k]=thresh/2^k with
// mem >= 0.75*thre[k]; out[t] = spike; mem -= spike.
//
// R1-R5: five structurally different kernels pinned at ~88us / 2.3 TB/s.
// R6: XCD-segmented j-sweep, BLOCK=256: kernel ~80us (2.5 TB/s).
// R7 FAILED (126us): per-thread 4-col chunk; compiler collapsed the pipeline,
//   grid = exactly 1 machine fill -> no TLP. Lesson: never per-thread loops.
// R8 FAILED (88us): BLOCK=1024 alone. CU-burst length is not the lever.
// R9 (this): ALIAS-BREAKING LDS ROTATION. All prior kernels access the 4
//   x-streams and 4 out-streams at the SAME column j, i.e. addresses
//   separated by exactly 2^25 B. If the DRAM bank hash aliases at 2^25,
//   every in-flight j is a 4-8-way row-thrash burst in one bank — matching
//   the 2.3 TB/s wall (copy ubench with only 2 streams: 6.29 TB/s).
//   Fix: per t-stream, the block loads columns rotated by t*256 (t*4KiB)
//   within its 1024-col chunk, staged via LDS; compute re-aligns columns;
//   stores leave with the same rotation. No thread ever has 2^25-aliased
//   addresses in flight.

constexpr int T_STEPS = 4;
constexpr int BLOCK   = 1024;   // one column per thread
constexpr int ROT     = 256;    // column rotation per t-stream (4 KiB)
constexpr int NXCD    = 8;

typedef float v4f __attribute__((ext_vector_type(4)));

// Exact spike via fp32 bit ordering (thresh > 0 normal, mem non-NaN):
// positive fp32 compare == int compare of bits; thr75[k] bits = b75_0 - k*2^23;
// k* = max(0, ceil((b75_0 - bits(mem)) / 2^23)); spike bits = bth0 - k*·2^23;
// mem < thr75[7] (incl. mem<=0, signed cmp) -> 0.  Verified absmax=0 R5-R8.
__device__ __forceinline__ float spike_of(float mem, int b75_0, int b75_7, int bth0) {
    int u = __float_as_int(mem);
    int d = (int)((unsigned)b75_0 - (unsigned)u);
    int k = (int)((unsigned)d + 0x7fffffu) >> 23;
    k = k > 0 ? k : 0;
    int sb = bth0 - (k << 23);
    return (u >= b75_7) ? __int_as_float(sb) : 0.0f;
}

__global__ __launch_bounds__(BLOCK) void snn_mth_kernel(
    const float* __restrict__ x,
    const float* __restrict__ p_thresh,
    float* __restrict__ out,
    int s4)   // float4 columns per timestep
{
    const float thresh = *p_thresh;
    const int bth0  = __float_as_int(thresh);
    const int b75_0 = __float_as_int(0.75f * thresh);
    const int b75_7 = b75_0 - 7 * 0x800000;

    const v4f* __restrict__ xv = reinterpret_cast<const v4f*>(x);
    v4f* __restrict__ ov = reinterpret_cast<v4f*>(out);

    __shared__ v4f lds[T_STEPS][BLOCK];   // 64 KiB -> 2 blocks/CU, 32 waves/CU

    // XCD-segmented mapping (R6): segment = b % NXCD (matches CP round-robin
    // block->XCD dispatch) so the 8 XCDs' fronts stay decorrelated.
    const int seg_cols   = s4 / (NXCD * BLOCK) * BLOCK;
    const int seg_blocks = seg_cols / BLOCK;
    const int main_blocks = seg_blocks * NXCD;

    const int b   = blockIdx.x;
    const int tid = threadIdx.x;
    const size_t n = (size_t)s4;

    if (b < main_blocks) {
        const int xcd  = b % NXCD;
        const int slot = b / NXCD;
        const size_t col0 = (size_t)xcd * seg_cols + (size_t)slot * BLOCK;

        // ---- rotated load phase: stream t read at columns col0 + (i + t*ROT)%BLOCK.
        // Within a wave all 4 loads are >=4KiB apart mod 2^25 (alias broken);
        // global access stays fully coalesced per wave.
#pragma unroll
        for (int t = 0; t < T_STEPS; ++t) {
            const int cw = (tid + t * ROT) & (BLOCK - 1);
            lds[t][cw] = xv[(size_t)t * n + col0 + cw];
        }
        __syncthreads();

        // ---- compute phase: thread owns column col0 + tid; scan over t.
        v4f xc[T_STEPS];
#pragma unroll
        for (int t = 0; t < T_STEPS; ++t)
            xc[t] = lds[t][tid];

        v4f sp[T_STEPS];
#pragma unroll
        for (int e = 0; e < 4; ++e) {
            float mem = xc[0][e];
            float s0 = spike_of(mem, b75_0, b75_7, bth0);
            sp[0][e] = s0;
            mem = mem - s0 + xc[1][e];
            float s1 = spike_of(mem, b75_0, b75_7, bth0);
            sp[1][e] = s1;
            mem = mem - s1 + xc[2][e];
            float s2 = spike_of(mem, b75_0, b75_7, bth0);
            sp[2][e] = s2;
            mem = mem - s2 + xc[3][e];
            sp[3][e] = spike_of(mem, b75_0, b75_7, bth0);
        }

        // ---- stage spikes, then rotated store phase (same alias-breaking).
        __syncthreads();
#pragma unroll
        for (int t = 0; t < T_STEPS; ++t)
            lds[t][tid] = sp[t];
        __syncthreads();
#pragma unroll
        for (int t = 0; t < T_STEPS; ++t) {
            const int cw = (tid + t * ROT) & (BLOCK - 1);
            __builtin_nontemporal_store(lds[t][cw], &ov[(size_t)t * n + col0 + cw]);
        }
    } else {
        // Tail (empty for the benchmark shape: s4 = 2^21 divides evenly).
        const size_t j = (size_t)NXCD * seg_cols + (size_t)(b - main_blocks) * BLOCK + tid;
        if (j >= n) return;
        v4f xc[T_STEPS];
#pragma unroll
        for (int t = 0; t < T_STEPS; ++t)
            xc[t] = xv[(size_t)t * n + j];
        v4f sp[T_STEPS];
#pragma unroll
        for (int e = 0; e < 4; ++e) {
            float mem = xc[0][e];
            float s0 = spike_of(mem, b75_0, b75_7, bth0);
            sp[0][e] = s0;
            mem = mem - s0 + xc[1][e];
            float s1 = spike_of(mem, b75_0, b75_7, bth0);
            sp[1][e] = s1;
            mem = mem - s1 + xc[2][e];
            float s2 = spike_of(mem, b75_0, b75_7, bth0);
            sp[2][e] = s2;
            mem = mem - s2 + xc[3][e];
            sp[3][e] = spike_of(mem, b75_0, b75_7, bth0);
        }
#pragma unroll
        for (int t = 0; t < T_STEPS; ++t)
            __builtin_nontemporal_store(sp[t], &ov[(size_t)t * n + j]);
    }
}

extern "C" void kernel_launch(void* const* d_in, const int* in_sizes, int n_in,
                              void* d_out, int out_size, void* d_ws, size_t ws_size,
                              hipStream_t stream) {
    const float* x = (const float*)d_in[0];
    const float* p_thresh = (const float*)d_in[1];
    float* out = (float*)d_out;

    const int total = in_sizes[0];          // T*B*C*H*W
    const int S = total / T_STEPS;          // spatial elements per timestep
    const int s4 = S >> 2;                  // float4 columns

    const int grid = (s4 + BLOCK - 1) / BLOCK;
    snn_mth_kernel<<<grid, BLOCK, 0, stream>>>(x, p_thresh, out, s4);
}